// Round 6
// baseline (400.289 us; speedup 1.0000x reference)
//
#include <hip/hip_runtime.h>
#include <stdint.h>

#define NA 9
#define NC 80
#define NTOT 589824        // 256*256*9
#define NT4  147456        // NTOT/4
#define TOPK 1000
#define CONF 0.05f
#define NMS_T 0.6
#define CTR_CLAMP 32.0
#define IMGF 2048.0
#define SCALE_CLAMP 4.135166556742356   // log(1000/16)

// ---- workspace byte offsets ----
// All sync words padded to 256B lines (round-2 lesson: agent-scope ops
// serialize per LLC line; shared line = ~30us/barrier).
#define HIST_OFF   4718592u    // 16384 u32 (64KB)
#define CNT_OFF    4784128u    // cand counter, own 256B line
#define BARC_OFF   4784384u    // 4 barriers x 8 counters, 256B stride (8192B)
#define FLAG_OFF   4792576u    // 4 barriers x 8 flag copies, 256B stride (8192B)
#define INITF_OFF  4800768u    // 8 init-done u64 magic flags, 256B stride (2048B)
#define CAND_OFF   4802816u    // 4096 u64 (32KB)
#define BOXES_OFF  4835584u    // 4000 f32
#define LABS_OFF   4851584u    // 1000 i32
#define SUPB_OFF   4855584u    // 16*1024 u64 transposed (128KB)

#define NBLK 512               // 64KB LDS -> exactly 2 blocks/CU -> 512 co-resident
#define PER_BLK 288            // 512*288 == NT4 exactly: perfectly balanced
#define SPIN_CAP 200000        // ~12ms fail-fast: deadlock -> wrong answer, not hang
#define INIT_MAGIC 0x9E3779B97F4A7C15ull   // distinct 32-bit halves

// ---- agent-scope (cross-XCD coherent, L2-bypassing) accessors ----
__device__ __forceinline__ void stg32(unsigned* p, unsigned v) {
  __hip_atomic_store(p, v, __ATOMIC_RELAXED, __HIP_MEMORY_SCOPE_AGENT);
}
__device__ __forceinline__ unsigned ldg32(const unsigned* p) {
  return __hip_atomic_load((unsigned*)p, __ATOMIC_RELAXED, __HIP_MEMORY_SCOPE_AGENT);
}
__device__ __forceinline__ void stg64(unsigned long long* p, unsigned long long v) {
  __hip_atomic_store(p, v, __ATOMIC_RELAXED, __HIP_MEMORY_SCOPE_AGENT);
}
__device__ __forceinline__ unsigned long long ldg64(const unsigned long long* p) {
  return __hip_atomic_load((unsigned long long*)p, __ATOMIC_RELAXED,
                           __HIP_MEMORY_SCOPE_AGENT);
}

__device__ __forceinline__ unsigned* lslot(unsigned* base, int idx) {
  return (unsigned*)((char*)base + (size_t)idx * 256u);
}

// Lightweight device barrier, no cache maintenance (verified rounds 4-5).
__device__ __forceinline__ void barrier_sync(unsigned* cnts, unsigned* flags,
                                             int b, int bid, unsigned target,
                                             bool i_arrive) {
  __syncthreads();
  if (threadIdx.x == 0) {
    if (i_arrive)
      __hip_atomic_fetch_add(lslot(cnts, b * 8 + (bid & 7)), 1u, __ATOMIC_RELAXED,
                             __HIP_MEMORY_SCOPE_AGENT);
    if (bid == 0) {
      for (int it = 0; it < SPIN_CAP; it++) {
        unsigned s = 0;
#pragma unroll
        for (int i = 0; i < 8; i++)
          s += __hip_atomic_load(lslot(cnts, b * 8 + i), __ATOMIC_RELAXED,
                                 __HIP_MEMORY_SCOPE_AGENT);
        if (s >= target) break;
        __builtin_amdgcn_s_sleep(2);
      }
#pragma unroll
      for (int i = 0; i < 8; i++)
        __hip_atomic_store(lslot(flags, b * 8 + i), 1u, __ATOMIC_RELAXED,
                           __HIP_MEMORY_SCOPE_AGENT);
    } else {
      for (int it = 0; it < SPIN_CAP; it++) {
        if (__hip_atomic_load(lslot(flags, b * 8 + (bid & 7)), __ATOMIC_RELAXED,
                              __HIP_MEMORY_SCOPE_AGENT) != 0u)
          break;
        __builtin_amdgcn_s_sleep(2);
      }
    }
  }
  __syncthreads();
  asm volatile("" ::: "memory");
}

// ---- cephes f32 exp/log (matches the CPU reference's rounding; DO NOT TOUCH) ----
__device__ __forceinline__ float cexpf(float x) {
#pragma clang fp contract(off)
  float m = floorf(__builtin_fmaf(x, 1.44269504088896341f, 0.5f));
  float r = __builtin_fmaf(m, -0.693359375f, x);
  r = __builtin_fmaf(m, 2.12194440e-4f, r);
  float r2 = r * r;
  float y = 1.9875691500E-4f;
  y = __builtin_fmaf(y, r, 1.3981999507E-3f);
  y = __builtin_fmaf(y, r, 8.3334519073E-3f);
  y = __builtin_fmaf(y, r, 4.1665795894E-2f);
  y = __builtin_fmaf(y, r, 1.6666665459E-1f);
  y = __builtin_fmaf(y, r, 5.0000001201E-1f);
  y = __builtin_fmaf(y, r2, r) + 1.0f;
  return ldexpf(y, (int)m);
}

__device__ __forceinline__ float clogf_(float xin) {
#pragma clang fp contract(off)
  unsigned b = __float_as_uint(xin);
  int e = (int)(b >> 23) - 126;
  float m = __uint_as_float((b & 0x007FFFFFu) | 0x3F000000u);
  if (m < 0.707106781186547524f) { e -= 1; m = m + m; }
  float x = m - 1.0f;
  float z = x * x;
  float y = 7.0376836292E-2f;
  y = __builtin_fmaf(y, x, -1.1514610310E-1f);
  y = __builtin_fmaf(y, x, 1.1676998740E-1f);
  y = __builtin_fmaf(y, x, -1.2420140846E-1f);
  y = __builtin_fmaf(y, x, 1.4249322787E-1f);
  y = __builtin_fmaf(y, x, -1.6668057665E-1f);
  y = __builtin_fmaf(y, x, 2.0000714765E-1f);
  y = __builtin_fmaf(y, x, -2.4999993993E-1f);
  y = __builtin_fmaf(y, x, 3.3333331174E-1f);
  y = y * x * z;
  float ef = (float)e;
  y = __builtin_fmaf(ef, -2.12194440e-4f, y);
  y = __builtin_fmaf(-0.5f, z, y);
  float res = x + y;
  res = __builtin_fmaf(ef, 0.693359375f, res);
  return res;
}

__device__ __forceinline__ unsigned long long shflxor64(unsigned long long v, int m) {
  unsigned lo = __shfl_xor((unsigned)v, m, 64);
  unsigned hi = __shfl_xor((unsigned)(v >> 32), m, 64);
  return ((unsigned long long)hi << 32) | lo;
}

// Score one float4-group t4: argmax over 80 classes + cephes score chain +
// LDS hist atomics. Results stay in the caller's registers.
__device__ __forceinline__ void score4(const float4* __restrict__ obj4,
                                       const float4* __restrict__ cls4,
                                       unsigned t4, unsigned bv[4], int bc[4],
                                       unsigned* lh) {
#pragma clang fp contract(off)
  int a = (int)(t4 >> 14);
  int rem = (int)(t4 & 16383u);
  float4 ov = obj4[t4];
  float ob[4] = {ov.x, ov.y, ov.z, ov.w};
  float best[4] = {-1e30f, -1e30f, -1e30f, -1e30f};
  bc[0] = bc[1] = bc[2] = bc[3] = 0;
  const float4* cp = cls4 + a * 80 * 16384 + rem;
#pragma unroll 8
  for (int c = 0; c < 80; c++) {
    float4 cv = cp[c * 16384];
    float cl[4] = {cv.x, cv.y, cv.z, cv.w};
#pragma unroll
    for (int k = 0; k < 4; k++) {
      if (cl[k] > best[k]) { best[k] = cl[k]; bc[k] = c; }  // strict >: first max
    }
  }
#pragma unroll
  for (int k = 0; k < 4; k++) {
    float c = best[k], o = ob[k];
    float ec = cexpf(c);
    float eo = cexpf(o);
    float L = clogf_((1.0f + ec) + eo);
    float nrm = (c + o) - L;
    float p = 1.0f / (1.0f + cexpf(-nrm));
    bv[k] = __float_as_uint(p);              // p in (0,1): order == bit order
    atomicAdd(&lh[bv[k] >> 16], 1u);
  }
}

// Single fused kernel v2: init + score (results register-resident) -> B0 ->
// cutoff(redundant) + register-compaction (label packed into key) -> B1 ->
// rank/decode -> B2 -> sup matrix -> B3 -> nms(block0).
// No bits_all/labels_all arrays at all: score's only global traffic is the
// histogram. Key = (bits<<27) | ((0xFFFFF-j)<<7) | label  (59 bits; order
// identical to (score desc, j asc) since j is unique; label never compared).
__global__ __launch_bounds__(256) void k_fused(
    const float4* __restrict__ obj4, const float4* __restrict__ cls4,
    unsigned* __restrict__ hist, const float* __restrict__ reg_pred,
    const float* __restrict__ anchors, unsigned* __restrict__ cand_cnt,
    unsigned* __restrict__ barc, unsigned* __restrict__ flags,
    unsigned* __restrict__ initf, unsigned long long* __restrict__ cand,
    float* __restrict__ out, float* __restrict__ boxes_s,
    int* __restrict__ labels_s, unsigned long long* __restrict__ supB) {
  int tid = threadIdx.x;
  int bid = blockIdx.x;

  __shared__ __align__(16) unsigned lh[16384];   // 64KB, overlaid per phase

  // ---- Phase 0: LDS hist zero (all blocks) + global sync-word init (block 0).
  for (int i = tid; i < 16384; i += 256) lh[i] = 0u;
  if (bid == 0) {
    for (int i = tid; i < 16384; i += 256) stg32(&hist[i], 0u);
    if (tid == 0) stg32(cand_cnt, 0u);
    if (tid < 32) {
      stg32(lslot(barc, tid), 0u);
      stg32(lslot(flags, tid), 0u);
    }
  }
  __syncthreads();   // lh zero visible; block0's global zeros drained (vmcnt)
  if (bid == 0 && tid < 8)
    stg64((unsigned long long*)lslot(initf, tid), INIT_MAGIC);

  // ---- Phase 1: score. Every block owns 288 contiguous groups; the 32 extra
  // groups are spread 8-per-wave so all waves do identical 1+1/8 passes. ----
  int lane = tid & 63, wv = tid >> 6;
  unsigned t4a = (unsigned)bid * PER_BLK + (unsigned)tid;
  unsigned t4b = (unsigned)bid * PER_BLK + 256u + (unsigned)(wv * 8 + lane);
  bool has1 = (lane < 8);
  unsigned bv0[4], bv1[4] = {0, 0, 0, 0};
  int bc0[4], bc1[4] = {0, 0, 0, 0};
  score4(obj4, cls4, t4a, bv0, bc0, lh);
  if (has1) score4(obj4, cls4, t4b, bv1, bc1, lh);

  __syncthreads();   // all lh atomics done
  // wait init-done before merging into global hist (block0 finished long ago)
  if (tid == 0) {
    for (int it = 0; it < SPIN_CAP; it++) {
      if (ldg64((unsigned long long*)lslot(initf, bid & 7)) == INIT_MAGIC) break;
      __builtin_amdgcn_s_sleep(2);
    }
  }
  __syncthreads();
  for (int b = tid; b < 16384; b += 256) {
    unsigned v = lh[b];
    if (v) atomicAdd(&hist[b], v);
  }
  barrier_sync(barc, flags, 0, bid, NBLK, true);

  // ---- Phase 2: cutoff bin, redundantly per block (plain loads: hist lines
  // only ever written via LLC ops -> first-touch L2 fill is fresh) ----
  unsigned cB;
  {
    unsigned base = (unsigned)tid * 64u;
    unsigned s = 0;
#pragma unroll 8
    for (int b = 0; b < 64; b++) s += hist[base + b];
    unsigned v = s;
    lh[tid] = v;
    __syncthreads();
    for (int off = 1; off < 256; off <<= 1) {
      unsigned add = (tid + off < 256) ? lh[tid + off] : 0u;
      __syncthreads();
      v += add;
      lh[tid] = v;
      __syncthreads();
    }
    unsigned nxt = (tid < 255) ? lh[tid + 1] : 0u;
    if (v >= TOPK && nxt < TOPK) { lh[260] = (unsigned)tid; lh[261] = nxt; }
    __syncthreads();
    unsigned C = lh[260];
    unsigned above = lh[261];
    if (tid < 64) {
      unsigned h = hist[C * 64u + (unsigned)tid];
      unsigned acc = h;
      for (int off = 1; off < 64; off <<= 1) {
        unsigned o = __shfl_down(acc, off, 64);
        if (tid + off < 64) acc += o;
      }
      acc += above;
      if (acc >= TOPK && (tid == 63 || (acc - h) < TOPK))
        lh[262] = C * 64u + (unsigned)tid;
    }
    __syncthreads();
    cB = lh[262];
  }

  // ---- Phase 3: compaction straight from registers (no bits_all readback) ----
  {
#pragma unroll
    for (int k = 0; k < 4; k++) {
      bool win = (bv0[k] >> 16) >= cB;
      unsigned long long m = __ballot(win);
      if (m != 0ull) {
        int leader = __ffsll((long long)m) - 1;
        unsigned base2 = 0;
        if (lane == leader) base2 = atomicAdd(cand_cnt, (unsigned)__popcll(m));
        base2 = __shfl(base2, leader, 64);
        if (win) {
          unsigned w = 4u * t4a + (unsigned)k;
          unsigned a = w >> 16, hw = w & 65535u;
          unsigned j = hw * 9u + a;
          unsigned pos = base2 + (unsigned)__popcll(m & ((1ull << lane) - 1ull));
          if (pos < 4096u)
            stg64(&cand[pos], ((unsigned long long)bv0[k] << 27) |
                                  ((unsigned long long)(0xFFFFFu - j) << 7) |
                                  (unsigned long long)(unsigned)bc0[k]);
        }
      }
    }
#pragma unroll
    for (int k = 0; k < 4; k++) {
      bool win = has1 && ((bv1[k] >> 16) >= cB);
      unsigned long long m = __ballot(win);
      if (m != 0ull) {
        int leader = __ffsll((long long)m) - 1;
        unsigned base2 = 0;
        if (lane == leader) base2 = atomicAdd(cand_cnt, (unsigned)__popcll(m));
        base2 = __shfl(base2, leader, 64);
        if (win) {
          unsigned w = 4u * t4b + (unsigned)k;
          unsigned a = w >> 16, hw = w & 65535u;
          unsigned j = hw * 9u + a;
          unsigned pos = base2 + (unsigned)__popcll(m & ((1ull << lane) - 1ull));
          if (pos < 4096u)
            stg64(&cand[pos], ((unsigned long long)bv1[k] << 27) |
                                  ((unsigned long long)(0xFFFFFu - j) << 7) |
                                  (unsigned long long)(unsigned)bc1[k]);
        }
      }
    }
  }
  barrier_sync(barc, flags, 1, bid, NBLK, true);

  // ---- Phase 4: rank-based top-1000 + box decode (blocks 0..15) ----
  if (bid < 16) {
    unsigned long long* s_key = (unsigned long long*)lh;
    int c = bid * 256 + tid;
    unsigned M = ldg32(cand_cnt);
    if (M > 4096u) M = 4096u;
    unsigned long long mykey = (c < (int)M) ? ldg64(&cand[c]) : 0ull;
    unsigned rank = 0;
    int ntile = (int)((M + 255u) >> 8);
    for (int tile = 0; tile < ntile; tile++) {
      __syncthreads();
      int src = tile * 256 + tid;
      s_key[tid] = (src < (int)M) ? ldg64(&cand[src]) : 0ull;
      __syncthreads();
#pragma unroll 8
      for (int q = 0; q < 256; q++) rank += (s_key[q] > mykey) ? 1u : 0u;
    }
    if (c < (int)M && rank < TOPK) {
      int r = (int)rank;
      int lab = (int)(mykey & 0x7Full);
      unsigned j = 0xFFFFFu - (unsigned)((mykey >> 7) & 0xFFFFFull);
      unsigned hw = j / 9u;
      unsigned a = j - hw * 9u;
      unsigned base = a * 4u * 65536u + hw;
      double r0 = (double)reg_pred[base];
      double r1 = (double)reg_pred[base + 65536u];
      double r2 = (double)reg_pred[base + 131072u];
      double r3 = (double)reg_pred[base + 196608u];
      double ax = (double)anchors[j * 4u + 0], ay = (double)anchors[j * 4u + 1];
      double aw = (double)anchors[j * 4u + 2], ah = (double)anchors[j * 4u + 3];
      double ox = fmin(fmax(r0 * aw, -CTR_CLAMP), CTR_CLAMP);
      double oy = fmin(fmax(r1 * ah, -CTR_CLAMP), CTR_CLAMP);
      double cx = ax + ox, cy = ay + oy;
      double ww = aw * exp(fmin(r2, SCALE_CLAMP));
      double hh = ah * exp(fmin(r3, SCALE_CLAMP));
      float x1 = (float)fmin(fmax((cx - 0.5 * ww) * (1.0 / IMGF), 0.0), 1.0);
      float y1 = (float)fmin(fmax((cy - 0.5 * hh) * (1.0 / IMGF), 0.0), 1.0);
      float x2 = (float)fmin(fmax((cx + 0.5 * ww) * (1.0 / IMGF), 0.0), 1.0);
      float y2 = (float)fmin(fmax((cy + 0.5 * hh) * (1.0 / IMGF), 0.0), 1.0);
      // final outputs read only by host: plain stores are fine
      out[1000 + r] = (float)lab;
      out[2000 + 4 * r + 0] = x1;
      out[2000 + 4 * r + 1] = y1;
      out[2000 + 4 * r + 2] = x2;
      out[2000 + 4 * r + 3] = y2;
      // values read by later phases: agent-scope publish
      stg32((unsigned*)&out[r], (unsigned)(mykey >> 27));
      stg32((unsigned*)&boxes_s[4 * r + 0], __float_as_uint(x1));
      stg32((unsigned*)&boxes_s[4 * r + 1], __float_as_uint(y1));
      stg32((unsigned*)&boxes_s[4 * r + 2], __float_as_uint(x2));
      stg32((unsigned*)&boxes_s[4 * r + 3], __float_as_uint(y2));
      stg32((unsigned*)&labels_s[r], (unsigned)lab);
    }
  }
  barrier_sync(barc, flags, 2, bid, 16, bid < 16);

  // ---- Phase 5: suppression bit-matrix (rows bid and bid+512) ----
  {
    float* s_bx = (float*)lh;
    int* s_lb = (int*)((char*)lh + 16000);
    for (int t = tid; t < 4000; t += 256)
      s_bx[t] = __uint_as_float(ldg32((const unsigned*)&boxes_s[t]));
    for (int t = tid; t < 1000; t += 256)
      s_lb[t] = (int)ldg32((const unsigned*)&labels_s[t]);
    __syncthreads();
    for (int half = 0; half < 2; half++) {
      int i = bid + half * NBLK;
      if (i < TOPK) {
        double ix1 = (double)s_bx[4 * i], iy1 = (double)s_bx[4 * i + 1];
        double ix2 = (double)s_bx[4 * i + 2], iy2 = (double)s_bx[4 * i + 3];
        double ia = (ix2 - ix1) * (iy2 - iy1);
        int il = s_lb[i];
        for (int rep = 0; rep < 4; rep++) {
          int j = rep * 256 + tid;
          bool s = false;
          if (j < TOPK && j > i && s_lb[j] == il) {
            double jx1 = (double)s_bx[4 * j], jy1 = (double)s_bx[4 * j + 1];
            double jx2 = (double)s_bx[4 * j + 2], jy2 = (double)s_bx[4 * j + 3];
            double xx1 = fmax(ix1, jx1), yy1 = fmax(iy1, jy1);
            double xx2 = fmin(ix2, jx2), yy2 = fmin(iy2, jy2);
            double inter = fmax(1e-28, xx2 - xx1) * fmax(1e-28, yy2 - yy1);
            double ja = (jx2 - jx1) * (jy2 - jy1);
            double iou = inter / (ia + ja - inter + 1e-14);
            s = iou > NMS_T;
          }
          unsigned long long w = __ballot(s);
          if ((tid & 63) == 0)
            stg64(&supB[(rep * 4 + (tid >> 6)) * 1024 + i], w);
        }
      }
    }
  }
  // barrier 3: everyone arrives; only block 0 waits (others exit, freeing CUs)
  __syncthreads();   // drain vmcnt: publishes supB
  if (tid == 0)
    __hip_atomic_fetch_add(lslot(barc, 3 * 8 + (bid & 7)), 1u, __ATOMIC_RELAXED,
                           __HIP_MEMORY_SCOPE_AGENT);
  if (bid != 0) return;
  if (tid == 0) {
    for (int it = 0; it < SPIN_CAP; it++) {
      unsigned s = 0;
#pragma unroll
      for (int i = 0; i < 8; i++)
        s += __hip_atomic_load(lslot(barc, 3 * 8 + i), __ATOMIC_RELAXED,
                               __HIP_MEMORY_SCOPE_AGENT);
      if (s >= NBLK) break;
      __builtin_amdgcn_s_sleep(2);
    }
  }
  __syncthreads();
  asm volatile("" ::: "memory");

  // ---- Phase 6: greedy NMS (block 0, wave 0) ----
  if (tid < 64) {
    float* keep_out = out + 6000;
    unsigned long long inval[16];
#pragma unroll
    for (int m = 0; m < 16; m++) {
      int j = m * 64 + lane;
      bool bad = (j >= TOPK) ||
                 (__uint_as_float(ldg32((const unsigned*)&out[j])) < CONF);
      inval[m] = __ballot(bad);
    }
    unsigned long long kept[16];
#pragma unroll
    for (int b = 0; b < 16; b++) {
      unsigned long long acc = 0ull;
#pragma unroll
      for (int m = 0; m < b; m++) {
        unsigned long long r = ldg64(&supB[b * 1024 + m * 64 + lane]);
        if ((kept[m] >> lane) & 1ull) acc |= r;
      }
      if (b > 0) {
#pragma unroll
        for (int s = 1; s < 64; s <<= 1) acc |= shflxor64(acc, s);
      }
      unsigned alo = __builtin_amdgcn_readfirstlane((unsigned)acc);
      unsigned ahi = __builtin_amdgcn_readfirstlane((unsigned)(acc >> 32));
      unsigned long long cur = inval[b] | (((unsigned long long)ahi << 32) | alo);
      unsigned long long diag = ldg64(&supB[b * 1024 + b * 64 + lane]);
      unsigned dlo = (unsigned)diag, dhi = (unsigned)(diag >> 32);
#pragma unroll 8
      for (int k = 0; k < 64; k++) {
        unsigned rlo = __builtin_amdgcn_readlane(dlo, k);
        unsigned rhi = __builtin_amdgcn_readlane(dhi, k);
        unsigned long long rk = ((unsigned long long)rhi << 32) | rlo;
        unsigned long long take = ((cur >> k) & 1ull) ? 0ull : rk;
        cur |= take;
      }
      kept[b] = ~cur;
    }
#pragma unroll
    for (int m = 0; m < 16; m++) {
      int j = m * 64 + lane;
      if (j < TOPK) keep_out[j] = ((kept[m] >> lane) & 1ull) ? 1.0f : 0.0f;
    }
  }
}

extern "C" void kernel_launch(void* const* d_in, const int* in_sizes, int n_in,
                              void* d_out, int out_size, void* d_ws, size_t ws_size,
                              hipStream_t stream) {
  const float* obj = (const float*)d_in[0];
  const float* cls = (const float*)d_in[1];
  const float* reg = (const float*)d_in[2];
  const float* anc = (const float*)d_in[3];
  float* out = (float*)d_out;
  char* ws = (char*)d_ws;

  const float4* obj4 = (const float4*)obj;
  const float4* cls4 = (const float4*)cls;
  unsigned* hist = (unsigned*)(ws + HIST_OFF);
  unsigned* cand_cnt = (unsigned*)(ws + CNT_OFF);
  unsigned* barc = (unsigned*)(ws + BARC_OFF);
  unsigned* flags = (unsigned*)(ws + FLAG_OFF);
  unsigned* initf = (unsigned*)(ws + INITF_OFF);
  unsigned long long* cand = (unsigned long long*)(ws + CAND_OFF);
  float* boxes_s = (float*)(ws + BOXES_OFF);
  int* labels_s = (int*)(ws + LABS_OFF);
  unsigned long long* supB = (unsigned long long*)(ws + SUPB_OFF);

  void* kargs[] = {(void*)&obj4,  (void*)&cls4,     (void*)&hist,
                   (void*)&reg,   (void*)&anc,      (void*)&cand_cnt,
                   (void*)&barc,  (void*)&flags,    (void*)&initf,
                   (void*)&cand,  (void*)&out,      (void*)&boxes_s,
                   (void*)&labels_s, (void*)&supB};
  hipLaunchCooperativeKernel((const void*)k_fused, dim3(NBLK), dim3(256), kargs, 0,
                             stream);
}

// Round 8
// 395.534 us; speedup vs baseline: 1.0120x; 1.0120x over previous
//
#include <hip/hip_runtime.h>
#include <stdint.h>

#define NA 9
#define NC 80
#define NTOT 589824        // 256*256*9
#define NT4  147456        // NTOT/4
#define TOPK 1000
#define CONF 0.05f
#define NMS_T 0.6
#define CTR_CLAMP 32.0
#define IMGF 2048.0
#define SCALE_CLAMP 4.135166556742356   // log(1000/16)

// ---- workspace byte offsets ----
// All sync words padded to 256B lines (round-2 lesson: agent-scope ops
// serialize per LLC line; shared line = ~30us/barrier).
#define HIST_OFF   4718592u    // 16384 u32 (64KB)
#define CNT_OFF    4784128u    // cand counter, own 256B line
#define BARC_OFF   4784384u    // 4 barriers x 8 counters, 256B stride (8192B)
#define FLAG_OFF   4792576u    // 4 barriers x 8 flag copies, 256B stride (8192B)
#define INITF_OFF  4800768u    // 8 init-done u64 magic flags, 256B stride (2048B)
#define CAND_OFF   4802816u    // 4096 u64 (32KB)
#define BOXES_OFF  4835584u    // 4000 f32
#define LABS_OFF   4851584u    // 1000 i32
#define SUPB_OFF   4855584u    // 16*1024 u64 transposed (128KB)

#define SPIN_CAP 200000        // ~12ms fail-fast: deadlock -> wrong answer, not hang
#define INIT_MAGIC 0x9E3779B97F4A7C15ull   // distinct 32-bit halves

// ---- agent-scope (cross-XCD coherent, L2-bypassing) accessors ----
__device__ __forceinline__ void stg32(unsigned* p, unsigned v) {
  __hip_atomic_store(p, v, __ATOMIC_RELAXED, __HIP_MEMORY_SCOPE_AGENT);
}
__device__ __forceinline__ unsigned ldg32(const unsigned* p) {
  return __hip_atomic_load((unsigned*)p, __ATOMIC_RELAXED, __HIP_MEMORY_SCOPE_AGENT);
}
__device__ __forceinline__ void stg64(unsigned long long* p, unsigned long long v) {
  __hip_atomic_store(p, v, __ATOMIC_RELAXED, __HIP_MEMORY_SCOPE_AGENT);
}
__device__ __forceinline__ unsigned long long ldg64(const unsigned long long* p) {
  return __hip_atomic_load((unsigned long long*)p, __ATOMIC_RELAXED,
                           __HIP_MEMORY_SCOPE_AGENT);
}

__device__ __forceinline__ unsigned* lslot(unsigned* base, int idx) {
  return (unsigned*)((char*)base + (size_t)idx * 256u);
}

// Lightweight device barrier, no cache maintenance (verified rounds 4-6).
__device__ __forceinline__ void barrier_sync(unsigned* cnts, unsigned* flags,
                                             int b, int bid, unsigned target,
                                             bool i_arrive) {
  __syncthreads();
  if (threadIdx.x == 0) {
    if (i_arrive)
      __hip_atomic_fetch_add(lslot(cnts, b * 8 + (bid & 7)), 1u, __ATOMIC_RELAXED,
                             __HIP_MEMORY_SCOPE_AGENT);
    if (bid == 0) {
      for (int it = 0; it < SPIN_CAP; it++) {
        unsigned s = 0;
#pragma unroll
        for (int i = 0; i < 8; i++)
          s += __hip_atomic_load(lslot(cnts, b * 8 + i), __ATOMIC_RELAXED,
                                 __HIP_MEMORY_SCOPE_AGENT);
        if (s >= target) break;
        __builtin_amdgcn_s_sleep(2);
      }
#pragma unroll
      for (int i = 0; i < 8; i++)
        __hip_atomic_store(lslot(flags, b * 8 + i), 1u, __ATOMIC_RELAXED,
                           __HIP_MEMORY_SCOPE_AGENT);
    } else {
      for (int it = 0; it < SPIN_CAP; it++) {
        if (__hip_atomic_load(lslot(flags, b * 8 + (bid & 7)), __ATOMIC_RELAXED,
                              __HIP_MEMORY_SCOPE_AGENT) != 0u)
          break;
        __builtin_amdgcn_s_sleep(2);
      }
    }
  }
  __syncthreads();
  asm volatile("" ::: "memory");
}

// ---- cephes f32 exp/log (matches the CPU reference's rounding; DO NOT TOUCH) ----
__device__ __forceinline__ float cexpf(float x) {
#pragma clang fp contract(off)
  float m = floorf(__builtin_fmaf(x, 1.44269504088896341f, 0.5f));
  float r = __builtin_fmaf(m, -0.693359375f, x);
  r = __builtin_fmaf(m, 2.12194440e-4f, r);
  float r2 = r * r;
  float y = 1.9875691500E-4f;
  y = __builtin_fmaf(y, r, 1.3981999507E-3f);
  y = __builtin_fmaf(y, r, 8.3334519073E-3f);
  y = __builtin_fmaf(y, r, 4.1665795894E-2f);
  y = __builtin_fmaf(y, r, 1.6666665459E-1f);
  y = __builtin_fmaf(y, r, 5.0000001201E-1f);
  y = __builtin_fmaf(y, r2, r) + 1.0f;
  return ldexpf(y, (int)m);
}

__device__ __forceinline__ float clogf_(float xin) {
#pragma clang fp contract(off)
  unsigned b = __float_as_uint(xin);
  int e = (int)(b >> 23) - 126;
  float m = __uint_as_float((b & 0x007FFFFFu) | 0x3F000000u);
  if (m < 0.707106781186547524f) { e -= 1; m = m + m; }
  float x = m - 1.0f;
  float z = x * x;
  float y = 7.0376836292E-2f;
  y = __builtin_fmaf(y, x, -1.1514610310E-1f);
  y = __builtin_fmaf(y, x, 1.1676998740E-1f);
  y = __builtin_fmaf(y, x, -1.2420140846E-1f);
  y = __builtin_fmaf(y, x, 1.4249322787E-1f);
  y = __builtin_fmaf(y, x, -1.6668057665E-1f);
  y = __builtin_fmaf(y, x, 2.0000714765E-1f);
  y = __builtin_fmaf(y, x, -2.4999993993E-1f);
  y = __builtin_fmaf(y, x, 3.3333331174E-1f);
  y = y * x * z;
  float ef = (float)e;
  y = __builtin_fmaf(ef, -2.12194440e-4f, y);
  y = __builtin_fmaf(-0.5f, z, y);
  float res = x + y;
  res = __builtin_fmaf(ef, 0.693359375f, res);
  return res;
}

__device__ __forceinline__ unsigned long long shflxor64(unsigned long long v, int m) {
  unsigned lo = __shfl_xor((unsigned)v, m, 64);
  unsigned hi = __shfl_xor((unsigned)(v >> 32), m, 64);
  return ((unsigned long long)hi << 32) | lo;
}

// Score one float4-group: 80-class argmax via ping-pong double-buffered loads
// (two 8xfloat4 register banks, 10 batches; batch s+1 in flight while batch s
// is consumed -> 8 outstanding loads sustained, no inter-batch drain). All
// indices compile-time (full unroll) so banks stay in registers (rule #20).
__device__ __forceinline__ void score4(const float4* __restrict__ obj4,
                                       const float4* __restrict__ cls4,
                                       unsigned t4, unsigned bv[4], int bc[4],
                                       unsigned* lh) {
#pragma clang fp contract(off)
  int a = (int)(t4 >> 14);
  int rem = (int)(t4 & 16383u);
  float4 ov = obj4[t4];
  float ob[4] = {ov.x, ov.y, ov.z, ov.w};
  float best[4] = {-1e30f, -1e30f, -1e30f, -1e30f};
  bc[0] = bc[1] = bc[2] = bc[3] = 0;
  const float4* cp = cls4 + a * 80 * 16384 + rem;
  float4 va[8], vb[8];
#pragma unroll
  for (int u = 0; u < 8; u++) va[u] = cp[u * 16384];
#pragma unroll
  for (int s = 0; s < 10; s++) {
    const float4* src = (s & 1) ? vb : va;   // s compile-time: static select
    float4* dst = (s & 1) ? va : vb;
    if (s < 9) {
#pragma unroll
      for (int u = 0; u < 8; u++) dst[u] = cp[((s + 1) * 8 + u) * 16384];
    }
#pragma unroll
    for (int u = 0; u < 8; u++) {
      int c = s * 8 + u;
      float cl[4] = {src[u].x, src[u].y, src[u].z, src[u].w};
#pragma unroll
      for (int k = 0; k < 4; k++) {
        if (cl[k] > best[k]) { best[k] = cl[k]; bc[k] = c; }  // strict >: first max
      }
    }
  }
#pragma unroll
  for (int k = 0; k < 4; k++) {
    float c = best[k], o = ob[k];
    float ec = cexpf(c);
    float eo = cexpf(o);
    float L = clogf_((1.0f + ec) + eo);
    float nrm = (c + o) - L;
    float p = 1.0f / (1.0f + cexpf(-nrm));
    bv[k] = __float_as_uint(p);              // p in (0,1): order == bit order
    // u16-packed hist: bin = bv>>16 (<16384); word = bin>>1, half = bin&1.
    // max increments per half per block <= 256*4*3 = 3072 < 65536: no carry.
    atomicAdd(&lh[bv[k] >> 17], 1u << (((bv[k] >> 16) & 1u) * 16u));
  }
}

// Single fused kernel v4 (grid-size adaptive): init + score (grid-stride, up to
// 3 register-resident results/thread) -> B0 -> cutoff(redundant) + register
// compaction (label in key) -> B1 -> rank/decode -> B2 -> sup matrix -> B3 ->
// nms(block0). LDS 32KB (u16 hist), overlaid per phase. Host picks the largest
// grid (576/512/256) the occupancy query proves co-resident.
__global__ __launch_bounds__(256, 3) void k_fused(
    const float4* __restrict__ obj4, const float4* __restrict__ cls4,
    unsigned* __restrict__ hist, const float* __restrict__ reg_pred,
    const float* __restrict__ anchors, unsigned* __restrict__ cand_cnt,
    unsigned* __restrict__ barc, unsigned* __restrict__ flags,
    unsigned* __restrict__ initf, unsigned long long* __restrict__ cand,
    float* __restrict__ out, float* __restrict__ boxes_s,
    int* __restrict__ labels_s, unsigned long long* __restrict__ supB) {
  int tid = threadIdx.x;
  int bid = blockIdx.x;
  int lane = tid & 63;
  unsigned nblk = gridDim.x;

  __shared__ __align__(16) unsigned lh[8192];   // 32KB, overlaid per phase

  // ---- Phase 0: LDS hist zero (all blocks) + global sync-word init (block 0).
  for (int i = tid; i < 8192; i += 256) lh[i] = 0u;
  if (bid == 0) {
    for (int i = tid; i < 16384; i += 256) stg32(&hist[i], 0u);
    if (tid == 0) stg32(cand_cnt, 0u);
    if (tid < 32) {
      stg32(lslot(barc, tid), 0u);
      stg32(lslot(flags, tid), 0u);
    }
  }
  __syncthreads();   // lh zero visible; block0's global zeros drained (vmcnt)
  if (bid == 0 && tid < 8)
    stg64((unsigned long long*)lslot(initf, tid), INIT_MAGIC);

  // ---- Phase 1: score, grid-stride; results stay in registers ----
  unsigned bvA[3][4];
  int bcA[3][4];
  unsigned tA[3];
  bool vld[3];
#pragma unroll
  for (int it = 0; it < 3; it++) {
    unsigned t4 = (unsigned)bid * 256u + (unsigned)tid + (unsigned)it * nblk * 256u;
    tA[it] = t4;
    vld[it] = (t4 < (unsigned)NT4);
    if (vld[it]) score4(obj4, cls4, t4, bvA[it], bcA[it], lh);
  }

  __syncthreads();   // all lh atomics done
  // wait init-done before merging into global hist (block0 finished long ago)
  if (tid == 0) {
    for (int it = 0; it < SPIN_CAP; it++) {
      if (ldg64((unsigned long long*)lslot(initf, bid & 7)) == INIT_MAGIC) break;
      __builtin_amdgcn_s_sleep(2);
    }
  }
  __syncthreads();
  for (int b = tid; b < 8192; b += 256) {
    unsigned w = lh[b];
    if (w & 0xFFFFu) atomicAdd(&hist[2 * b], w & 0xFFFFu);
    if (w >> 16) atomicAdd(&hist[2 * b + 1], w >> 16);
  }
  barrier_sync(barc, flags, 0, bid, nblk, true);

  // ---- Phase 2: cutoff bin, redundantly per block (plain loads: hist lines
  // only ever written via LLC ops -> first-touch L2 fill is fresh) ----
  unsigned cB;
  {
    unsigned base = (unsigned)tid * 64u;
    unsigned s = 0;
#pragma unroll 8
    for (int b = 0; b < 64; b++) s += hist[base + b];
    unsigned v = s;
    lh[tid] = v;
    __syncthreads();
    for (int off = 1; off < 256; off <<= 1) {
      unsigned add = (tid + off < 256) ? lh[tid + off] : 0u;
      __syncthreads();
      v += add;
      lh[tid] = v;
      __syncthreads();
    }
    unsigned nxt = (tid < 255) ? lh[tid + 1] : 0u;
    if (v >= TOPK && nxt < TOPK) { lh[260] = (unsigned)tid; lh[261] = nxt; }
    __syncthreads();
    unsigned C = lh[260];
    unsigned above = lh[261];
    if (tid < 64) {
      unsigned h = hist[C * 64u + (unsigned)tid];
      unsigned acc = h;
      for (int off = 1; off < 64; off <<= 1) {
        unsigned o = __shfl_down(acc, off, 64);
        if (tid + off < 64) acc += o;
      }
      acc += above;
      if (acc >= TOPK && (tid == 63 || (acc - h) < TOPK))
        lh[262] = C * 64u + (unsigned)tid;
    }
    __syncthreads();
    cB = lh[262];
  }

  // ---- Phase 3: compaction straight from registers (label packed into key:
  // key = bits<<27 | (0xFFFF F-j)<<7 | label; order == (score desc, j asc)) ----
  {
#pragma unroll
    for (int it = 0; it < 3; it++) {
#pragma unroll
      for (int k = 0; k < 4; k++) {
        bool win = vld[it] && ((bvA[it][k] >> 16) >= cB);
        unsigned long long m = __ballot(win);
        if (m != 0ull) {
          int leader = __ffsll((long long)m) - 1;
          unsigned base2 = 0;
          if (lane == leader) base2 = atomicAdd(cand_cnt, (unsigned)__popcll(m));
          base2 = __shfl(base2, leader, 64);
          if (win) {
            unsigned w = 4u * tA[it] + (unsigned)k;
            unsigned a = w >> 16, hw = w & 65535u;
            unsigned j = hw * 9u + a;
            unsigned pos = base2 + (unsigned)__popcll(m & ((1ull << lane) - 1ull));
            if (pos < 4096u)
              stg64(&cand[pos], ((unsigned long long)bvA[it][k] << 27) |
                                    ((unsigned long long)(0xFFFFFu - j) << 7) |
                                    (unsigned long long)(unsigned)bcA[it][k]);
          }
        }
      }
    }
  }
  barrier_sync(barc, flags, 1, bid, nblk, true);

  // ---- Phase 4: rank-based top-1000 + box decode (blocks 0..15) ----
  if (bid < 16) {
    unsigned long long* s_key = (unsigned long long*)lh;
    int c = bid * 256 + tid;
    unsigned M = ldg32(cand_cnt);
    if (M > 4096u) M = 4096u;
    unsigned long long mykey = (c < (int)M) ? ldg64(&cand[c]) : 0ull;
    unsigned rank = 0;
    int ntile = (int)((M + 255u) >> 8);
    for (int tile = 0; tile < ntile; tile++) {
      __syncthreads();
      int src = tile * 256 + tid;
      s_key[tid] = (src < (int)M) ? ldg64(&cand[src]) : 0ull;
      __syncthreads();
#pragma unroll 8
      for (int q = 0; q < 256; q++) rank += (s_key[q] > mykey) ? 1u : 0u;
    }
    if (c < (int)M && rank < TOPK) {
      int r = (int)rank;
      int lab = (int)(mykey & 0x7Full);
      unsigned j = 0xFFFFFu - (unsigned)((mykey >> 7) & 0xFFFFFull);
      unsigned hw = j / 9u;
      unsigned a = j - hw * 9u;
      unsigned base = a * 4u * 65536u + hw;
      double r0 = (double)reg_pred[base];
      double r1 = (double)reg_pred[base + 65536u];
      double r2 = (double)reg_pred[base + 131072u];
      double r3 = (double)reg_pred[base + 196608u];
      double ax = (double)anchors[j * 4u + 0], ay = (double)anchors[j * 4u + 1];
      double aw = (double)anchors[j * 4u + 2], ah = (double)anchors[j * 4u + 3];
      double ox = fmin(fmax(r0 * aw, -CTR_CLAMP), CTR_CLAMP);
      double oy = fmin(fmax(r1 * ah, -CTR_CLAMP), CTR_CLAMP);
      double cx = ax + ox, cy = ay + oy;
      double ww = aw * exp(fmin(r2, SCALE_CLAMP));
      double hh = ah * exp(fmin(r3, SCALE_CLAMP));
      float x1 = (float)fmin(fmax((cx - 0.5 * ww) * (1.0 / IMGF), 0.0), 1.0);
      float y1 = (float)fmin(fmax((cy - 0.5 * hh) * (1.0 / IMGF), 0.0), 1.0);
      float x2 = (float)fmin(fmax((cx + 0.5 * ww) * (1.0 / IMGF), 0.0), 1.0);
      float y2 = (float)fmin(fmax((cy + 0.5 * hh) * (1.0 / IMGF), 0.0), 1.0);
      // final outputs read only by host: plain stores are fine
      out[1000 + r] = (float)lab;
      out[2000 + 4 * r + 0] = x1;
      out[2000 + 4 * r + 1] = y1;
      out[2000 + 4 * r + 2] = x2;
      out[2000 + 4 * r + 3] = y2;
      // values read by later phases: agent-scope publish
      stg32((unsigned*)&out[r], (unsigned)(mykey >> 27));
      stg32((unsigned*)&boxes_s[4 * r + 0], __float_as_uint(x1));
      stg32((unsigned*)&boxes_s[4 * r + 1], __float_as_uint(y1));
      stg32((unsigned*)&boxes_s[4 * r + 2], __float_as_uint(x2));
      stg32((unsigned*)&boxes_s[4 * r + 3], __float_as_uint(y2));
      stg32((unsigned*)&labels_s[r], (unsigned)lab);
    }
  }
  barrier_sync(barc, flags, 2, bid, 16, bid < 16);

  // ---- Phase 5: suppression bit-matrix (rows strided by grid size) ----
  {
    float* s_bx = (float*)lh;
    int* s_lb = (int*)((char*)lh + 16000);
    for (int t = tid; t < 4000; t += 256)
      s_bx[t] = __uint_as_float(ldg32((const unsigned*)&boxes_s[t]));
    for (int t = tid; t < 1000; t += 256)
      s_lb[t] = (int)ldg32((const unsigned*)&labels_s[t]);
    __syncthreads();
    for (int i = bid; i < TOPK; i += (int)nblk) {
      double ix1 = (double)s_bx[4 * i], iy1 = (double)s_bx[4 * i + 1];
      double ix2 = (double)s_bx[4 * i + 2], iy2 = (double)s_bx[4 * i + 3];
      double ia = (ix2 - ix1) * (iy2 - iy1);
      int il = s_lb[i];
      for (int rep = 0; rep < 4; rep++) {
        int j = rep * 256 + tid;
        bool s = false;
        if (j < TOPK && j > i && s_lb[j] == il) {
          double jx1 = (double)s_bx[4 * j], jy1 = (double)s_bx[4 * j + 1];
          double jx2 = (double)s_bx[4 * j + 2], jy2 = (double)s_bx[4 * j + 3];
          double xx1 = fmax(ix1, jx1), yy1 = fmax(iy1, jy1);
          double xx2 = fmin(ix2, jx2), yy2 = fmin(iy2, jy2);
          double inter = fmax(1e-28, xx2 - xx1) * fmax(1e-28, yy2 - yy1);
          double ja = (jx2 - jx1) * (jy2 - jy1);
          double iou = inter / (ia + ja - inter + 1e-14);
          s = iou > NMS_T;
        }
        unsigned long long w = __ballot(s);
        if ((tid & 63) == 0)
          stg64(&supB[(rep * 4 + (tid >> 6)) * 1024 + i], w);
      }
    }
  }
  // barrier 3: everyone arrives; only block 0 waits (others exit, freeing CUs)
  __syncthreads();   // drain vmcnt: publishes supB
  if (tid == 0)
    __hip_atomic_fetch_add(lslot(barc, 3 * 8 + (bid & 7)), 1u, __ATOMIC_RELAXED,
                           __HIP_MEMORY_SCOPE_AGENT);
  if (bid != 0) return;
  if (tid == 0) {
    for (int it = 0; it < SPIN_CAP; it++) {
      unsigned s = 0;
#pragma unroll
      for (int i = 0; i < 8; i++)
        s += __hip_atomic_load(lslot(barc, 3 * 8 + i), __ATOMIC_RELAXED,
                               __HIP_MEMORY_SCOPE_AGENT);
      if (s >= nblk) break;
      __builtin_amdgcn_s_sleep(2);
    }
  }
  __syncthreads();
  asm volatile("" ::: "memory");

  // ---- Phase 6: greedy NMS (block 0, wave 0) ----
  if (tid < 64) {
    float* keep_out = out + 6000;
    unsigned long long inval[16];
#pragma unroll
    for (int m = 0; m < 16; m++) {
      int j = m * 64 + lane;
      bool bad = (j >= TOPK) ||
                 (__uint_as_float(ldg32((const unsigned*)&out[j])) < CONF);
      inval[m] = __ballot(bad);
    }
    unsigned long long kept[16];
#pragma unroll
    for (int b = 0; b < 16; b++) {
      unsigned long long acc = 0ull;
#pragma unroll
      for (int m = 0; m < b; m++) {
        unsigned long long r = ldg64(&supB[b * 1024 + m * 64 + lane]);
        if ((kept[m] >> lane) & 1ull) acc |= r;
      }
      if (b > 0) {
#pragma unroll
        for (int s = 1; s < 64; s <<= 1) acc |= shflxor64(acc, s);
      }
      unsigned alo = __builtin_amdgcn_readfirstlane((unsigned)acc);
      unsigned ahi = __builtin_amdgcn_readfirstlane((unsigned)(acc >> 32));
      unsigned long long cur = inval[b] | (((unsigned long long)ahi << 32) | alo);
      unsigned long long diag = ldg64(&supB[b * 1024 + b * 64 + lane]);
      unsigned dlo = (unsigned)diag, dhi = (unsigned)(diag >> 32);
#pragma unroll 8
      for (int k = 0; k < 64; k++) {
        unsigned rlo = __builtin_amdgcn_readlane(dlo, k);
        unsigned rhi = __builtin_amdgcn_readlane(dhi, k);
        unsigned long long rk = ((unsigned long long)rhi << 32) | rlo;
        unsigned long long take = ((cur >> k) & 1ull) ? 0ull : rk;
        cur |= take;
      }
      kept[b] = ~cur;
    }
#pragma unroll
    for (int m = 0; m < 16; m++) {
      int j = m * 64 + lane;
      if (j < TOPK) keep_out[j] = ((kept[m] >> lane) & 1ull) ? 1.0f : 0.0f;
    }
  }
}

extern "C" void kernel_launch(void* const* d_in, const int* in_sizes, int n_in,
                              void* d_out, int out_size, void* d_ws, size_t ws_size,
                              hipStream_t stream) {
  const float* obj = (const float*)d_in[0];
  const float* cls = (const float*)d_in[1];
  const float* reg = (const float*)d_in[2];
  const float* anc = (const float*)d_in[3];
  float* out = (float*)d_out;
  char* ws = (char*)d_ws;

  const float4* obj4 = (const float4*)obj;
  const float4* cls4 = (const float4*)cls;
  unsigned* hist = (unsigned*)(ws + HIST_OFF);
  unsigned* cand_cnt = (unsigned*)(ws + CNT_OFF);
  unsigned* barc = (unsigned*)(ws + BARC_OFF);
  unsigned* flags = (unsigned*)(ws + FLAG_OFF);
  unsigned* initf = (unsigned*)(ws + INITF_OFF);
  unsigned long long* cand = (unsigned long long*)(ws + CAND_OFF);
  float* boxes_s = (float*)(ws + BOXES_OFF);
  int* labels_s = (int*)(ws + LABS_OFF);
  unsigned long long* supB = (unsigned long long*)(ws + SUPB_OFF);

  // Occupancy-guarded cooperative grid: pick the largest grid that is provably
  // co-resident (round-7 lesson: an infeasible cooperative launch is silently
  // rejected and the output stays zero). Pure query: graph-capture-safe.
  int maxb = 0;
  if (hipOccupancyMaxActiveBlocksPerMultiprocessor(&maxb, k_fused, 256, 0) !=
          hipSuccess ||
      maxb <= 0)
    maxb = 2;
  int nblk = (maxb >= 3) ? 576 : ((maxb >= 2) ? 512 : 256);

  void* kargs[] = {(void*)&obj4,  (void*)&cls4,     (void*)&hist,
                   (void*)&reg,   (void*)&anc,      (void*)&cand_cnt,
                   (void*)&barc,  (void*)&flags,    (void*)&initf,
                   (void*)&cand,  (void*)&out,      (void*)&boxes_s,
                   (void*)&labels_s, (void*)&supB};
  hipLaunchCooperativeKernel((const void*)k_fused, dim3(nblk), dim3(256), kargs, 0,
                             stream);
}